// Round 4
// baseline (86.936 us; speedup 1.0000x reference)
//
#include <hip/hip_runtime.h>
#include <hip/hip_fp16.h>

// RoIAlign (legacy, grid spacing roi/(P-1), PH=PW=8, zero for OOR samples)
// fused with 2x2 stride-1 max-pool -> out [R, C=256, 7, 7] float32.
//
// R4: features channels-last f16 [B,H,W,C] (56 MB, L3-resident).
// Main kernel: thread = channel QUAD (one 8B float2 = 4 f16 channels per
// corner load), 4 row-groups (out rows {0,1},{2,3},{4,5},{6}); pooled rows
// written incrementally into a full 49 KB LDS slab (keeps VGPR low), then
// one dense float4 writeout.

#define FH 200
#define FW 272
#define FC 256
#define FHW (FH * FW)          // 54400
#define SPATIAL_SCALE 0.25f
#define PIX (FC / 4)           // pixel stride in float2(=4 f16) units: 64

// ---------------- transpose+convert [B,C,HW] f32 -> [B,HW,C] f16 ----------
__global__ __launch_bounds__(256) void transpose_f16_kernel(
    const float* __restrict__ in, __half* __restrict__ outT)
{
    __shared__ float tile[64][65];
    const int hw0  = blockIdx.x * 64;
    const int c0   = blockIdx.y * 64;
    const int b    = blockIdx.z;
    const int lane = threadIdx.x & 63;
    const int sub  = threadIdx.x >> 6;   // 0..3

    const float* inb = in + (size_t)b * FC * FHW;
    #pragma unroll
    for (int i = 0; i < 16; ++i) {
        const int c = sub * 16 + i;
        tile[c][lane] = inb[(size_t)(c0 + c) * FHW + hw0 + lane];
    }
    __syncthreads();
    __half* outb = outT + (size_t)b * FHW * FC;
    #pragma unroll
    for (int i = 0; i < 16; ++i) {
        const int hw = sub * 16 + i;
        outb[(size_t)(hw0 + hw) * FC + c0 + lane] = __float2half(tile[lane][hw]);
    }
}

// ---------------- main: f16 channels-last gather + fused pool -------------
__global__ __launch_bounds__(256) void roi_align_max_f16q_kernel(
    const float2* __restrict__ featT,   // [B, H, W, C/4] float2 (4 f16 ch)
    const float* __restrict__ rois,     // [R, 5]
    float* __restrict__ out,            // [R, C, 7, 7]
    int R)
{
    __shared__ int   s_off[64];          // (y0*W + x0) * PIX (float2 units)
    __shared__ float s_w0[64], s_w1[64], s_w2[64], s_w3[64];
    __shared__ int   s_base;             // b * H*W*PIX
    __shared__ float s_out[FC * 49];     // 49 KB output slab

    const int r   = blockIdx.x;
    const int tid = threadIdx.x;

    if (tid < 64) {
        const float b  = rois[r * 5 + 0];
        const float x1 = rois[r * 5 + 1] * SPATIAL_SCALE;
        const float y1 = rois[r * 5 + 2] * SPATIAL_SCALE;
        const float x2 = rois[r * 5 + 3] * SPATIAL_SCALE;
        const float y2 = rois[r * 5 + 4] * SPATIAL_SCALE;
        const float bin_h = fmaxf(y2 - y1, 0.0f) * (1.0f / 7.0f);
        const float bin_w = fmaxf(x2 - x1, 0.0f) * (1.0f / 7.0f);

        const int ph = tid >> 3;
        const int pw = tid & 7;
        const float h = y1 + (float)ph * bin_h;
        const float w = x1 + (float)pw * bin_w;

        const bool valid = (h >= 0.0f) && (h < (float)FH) &&
                           (w >= 0.0f) && (w < (float)FW);
        // legacy: clip floor() into [0, H-2]; fractions NOT re-clamped
        const float h0 = fminf(fmaxf(floorf(h), 0.0f), (float)(FH - 2));
        const float w0 = fminf(fmaxf(floorf(w), 0.0f), (float)(FW - 2));
        const float fh = h - h0;
        const float fw = w - w0;
        const float v  = valid ? 1.0f : 0.0f;

        s_off[tid] = ((int)h0 * FW + (int)w0) * PIX;
        s_w0[tid] = (1.0f - fh) * (1.0f - fw) * v;
        s_w1[tid] = (1.0f - fh) * fw * v;
        s_w2[tid] = fh * (1.0f - fw) * v;
        s_w3[tid] = fh * fw * v;
        if (tid == 0) s_base = (int)b * (FHW * PIX);
    }
    __syncthreads();

    const int cq = tid & 63;   // channel quad: channels 4cq..4cq+3
    const int g  = tid >> 6;   // row group: out rows {2g, 2g+1} (g=3: row 6)
    const float2* __restrict__ f = featT + s_base + cq;

    const int row0 = 2 * g;                 // first aligned row this group
    const int nout = (g < 3) ? 2 : 1;       // out rows produced

    float4 prev[8], cur[8];

    // sample one aligned row (8 grid points, 4 channels) into dst
    auto sample_row = [&](int ar, float4* dst) {
        #pragma unroll
        for (int pw = 0; pw < 8; ++pw) {
            const int m = ar * 8 + pw;
            const int o = s_off[m];
            float2 r00 = f[o];
            float2 r01 = f[o + PIX];
            float2 r10 = f[o + FW * PIX];
            float2 r11 = f[o + FW * PIX + PIX];
            const float w0v = s_w0[m], w1v = s_w1[m];
            const float w2v = s_w2[m], w3v = s_w3[m];
            const float2 p00 = __half22float2(((const __half2*)&r00)[0]);
            const float2 q00 = __half22float2(((const __half2*)&r00)[1]);
            const float2 p01 = __half22float2(((const __half2*)&r01)[0]);
            const float2 q01 = __half22float2(((const __half2*)&r01)[1]);
            const float2 p10 = __half22float2(((const __half2*)&r10)[0]);
            const float2 q10 = __half22float2(((const __half2*)&r10)[1]);
            const float2 p11 = __half22float2(((const __half2*)&r11)[0]);
            const float2 q11 = __half22float2(((const __half2*)&r11)[1]);
            dst[pw].x = p00.x * w0v + p01.x * w1v + p10.x * w2v + p11.x * w3v;
            dst[pw].y = p00.y * w0v + p01.y * w1v + p10.y * w2v + p11.y * w3v;
            dst[pw].z = q00.x * w0v + q01.x * w1v + q10.x * w2v + q11.x * w3v;
            dst[pw].w = q00.y * w0v + q01.y * w1v + q10.y * w2v + q11.y * w3v;
        }
    };

    sample_row(row0, prev);
    #pragma unroll
    for (int j = 0; j < 2; ++j) {
        if (j < nout) {
            sample_row(row0 + 1 + j, cur);
            const int oh = row0 + j;
            const int cbase = cq * 4;
            #pragma unroll
            for (int ow = 0; ow < 7; ++ow) {
                float4 mx;
                mx.x = fmaxf(fmaxf(prev[ow].x, prev[ow + 1].x),
                             fmaxf(cur[ow].x,  cur[ow + 1].x));
                mx.y = fmaxf(fmaxf(prev[ow].y, prev[ow + 1].y),
                             fmaxf(cur[ow].y,  cur[ow + 1].y));
                mx.z = fmaxf(fmaxf(prev[ow].z, prev[ow + 1].z),
                             fmaxf(cur[ow].z,  cur[ow + 1].z));
                mx.w = fmaxf(fmaxf(prev[ow].w, prev[ow + 1].w),
                             fmaxf(cur[ow].w,  cur[ow + 1].w));
                s_out[(cbase + 0) * 49 + oh * 7 + ow] = mx.x;
                s_out[(cbase + 1) * 49 + oh * 7 + ow] = mx.y;
                s_out[(cbase + 2) * 49 + oh * 7 + ow] = mx.z;
                s_out[(cbase + 3) * 49 + oh * 7 + ow] = mx.w;
            }
            #pragma unroll
            for (int pw = 0; pw < 8; ++pw) prev[pw] = cur[pw];
        }
    }
    __syncthreads();

    // dense float4 writeout of this roi's [C,7,7] slab
    const float4* s4 = (const float4*)s_out;
    float4* o4 = (float4*)(out + (size_t)r * (FC * 49));
    #pragma unroll
    for (int k = 0; k < 13; ++k) {
        const int idx = k * 256 + tid;
        if (idx < (FC * 49 / 4)) o4[idx] = s4[idx];
    }
}

// ---------------- fallback (NCHW direct) if ws too small ------------------
__global__ __launch_bounds__(256) void roi_align_max_kernel(
    const float* __restrict__ feat, const float* __restrict__ rois,
    float* __restrict__ out, int R)
{
    __shared__ int   s_off[64];
    __shared__ float s_w0[64], s_w1[64], s_w2[64], s_w3[64];
    __shared__ int   s_base;

    const int r   = blockIdx.x;
    const int tid = threadIdx.x;

    if (tid < 64) {
        const float b  = rois[r * 5 + 0];
        const float x1 = rois[r * 5 + 1] * SPATIAL_SCALE;
        const float y1 = rois[r * 5 + 2] * SPATIAL_SCALE;
        const float x2 = rois[r * 5 + 3] * SPATIAL_SCALE;
        const float y2 = rois[r * 5 + 4] * SPATIAL_SCALE;
        const float bin_h = fmaxf(y2 - y1, 0.0f) * (1.0f / 7.0f);
        const float bin_w = fmaxf(x2 - x1, 0.0f) * (1.0f / 7.0f);
        const int ph = tid >> 3;
        const int pw = tid & 7;
        const float h = y1 + (float)ph * bin_h;
        const float w = x1 + (float)pw * bin_w;
        const bool valid = (h >= 0.0f) && (h < (float)FH) &&
                           (w >= 0.0f) && (w < (float)FW);
        const float h0 = fminf(fmaxf(floorf(h), 0.0f), (float)(FH - 2));
        const float w0 = fminf(fmaxf(floorf(w), 0.0f), (float)(FW - 2));
        const float fh = h - h0;
        const float fw = w - w0;
        const float v  = valid ? 1.0f : 0.0f;
        s_off[tid] = (int)h0 * FW + (int)w0;
        s_w0[tid] = (1.0f - fh) * (1.0f - fw) * v;
        s_w1[tid] = (1.0f - fh) * fw * v;
        s_w2[tid] = fh * (1.0f - fw) * v;
        s_w3[tid] = fh * fw * v;
        if (tid == 0) s_base = (int)b * (FC * FHW);
    }
    __syncthreads();

    const int c = tid;
    const float* __restrict__ f = feat + s_base + c * FHW;
    float* __restrict__ outp = out + ((size_t)r * FC + c) * 49;

    float prev[8];
    for (int ph = 0; ph < 8; ++ph) {
        float cur[8];
        #pragma unroll
        for (int pw = 0; pw < 8; ++pw) {
            const int m = ph * 8 + pw;
            const int o = s_off[m];
            cur[pw] = f[o] * s_w0[m] + f[o + 1] * s_w1[m]
                    + f[o + FW] * s_w2[m] + f[o + FW + 1] * s_w3[m];
        }
        if (ph > 0) {
            #pragma unroll
            for (int ow = 0; ow < 7; ++ow)
                outp[(ph - 1) * 7 + ow] =
                    fmaxf(fmaxf(prev[ow], prev[ow + 1]),
                          fmaxf(cur[ow],  cur[ow + 1]));
        }
        #pragma unroll
        for (int pw = 0; pw < 8; ++pw) prev[pw] = cur[pw];
    }
}

extern "C" void kernel_launch(void* const* d_in, const int* in_sizes, int n_in,
                              void* d_out, int out_size, void* d_ws, size_t ws_size,
                              hipStream_t stream) {
    const float* feat = (const float*)d_in[0];
    const float* rois = (const float*)d_in[1];
    float* out = (float*)d_out;
    const int R = in_sizes[1] / 5;
    if (R <= 0) return;

    const size_t needed = (size_t)2 * FC * FHW * sizeof(__half);  // 55.7 MB
    if (ws_size >= needed) {
        __half* featT = (__half*)d_ws;
        transpose_f16_kernel<<<dim3(FHW / 64, FC / 64, 2), 256, 0, stream>>>(feat, featT);
        roi_align_max_f16q_kernel<<<R, 256, 0, stream>>>(
            (const float2*)featT, rois, out, R);
    } else {
        roi_align_max_kernel<<<R, 256, 0, stream>>>(feat, rois, out, R);
    }
}